// Round 4
// baseline (615116.992 us; speedup 1.0000x reference)
//
#include <hip/hip_runtime.h>
#include <hip/hip_fp16.h>
#include <math.h>

#define T_LEN 2048
#define NB 8
#define DD 512
#define HH 512
#define G4 2048   // 4*H
#define CAT2H 1024

// ---------- vector load/store helpers (fp32 or fp16 <-> float4) ----------
__device__ __forceinline__ float4 ld4(const float* p) { return *(const float4*)p; }
__device__ __forceinline__ float4 ld4(const __half* p) {
  const __half2 a = *(const __half2*)p;
  const __half2 b = *(const __half2*)(p + 2);
  return make_float4(__half2float(a.x), __half2float(a.y),
                     __half2float(b.x), __half2float(b.y));
}
__device__ __forceinline__ void st4(float* p, float4 v) { *(float4*)p = v; }
__device__ __forceinline__ void st4(__half* p, float4 v) {
  *(__half2*)p = __floats2half2_rn(v.x, v.y);
  *(__half2*)(p + 2) = __floats2half2_rn(v.z, v.w);
}

// ---------------- tiled GEMM with bias: C = A(MxK) @ B(KxN) + bias ----------------
template <typename TA, typename TC>
__global__ __launch_bounds__(256) void gemm_bias(
    const TA* __restrict__ A, const float* __restrict__ B,
    const float* __restrict__ bias, TC* __restrict__ C,
    int M, int N, int K) {
  __shared__ float As[16][128];
  __shared__ float Bs[16][128];
  const int nTiles = N >> 7;
  const int bx = blockIdx.x % nTiles;
  const int by = blockIdx.x / nTiles;
  const int tid = threadIdx.x;
  const int tx = tid & 15, ty = tid >> 4;
  const TA* Ab = A + (size_t)by * 128 * K;
  const float* Bb = B + ((size_t)bx << 7);
  float acc[8][8];
#pragma unroll
  for (int i = 0; i < 8; i++)
#pragma unroll
    for (int j = 0; j < 8; j++) acc[i][j] = 0.f;

  for (int k0 = 0; k0 < K; k0 += 16) {
    __syncthreads();
#pragma unroll
    for (int i = 0; i < 2; i++) {
      int idx = i * 256 + tid;
      int m = idx >> 2, kv = idx & 3;
      float4 va = ld4(Ab + (size_t)m * K + k0 + kv * 4);
      As[kv * 4 + 0][m] = va.x;
      As[kv * 4 + 1][m] = va.y;
      As[kv * 4 + 2][m] = va.z;
      As[kv * 4 + 3][m] = va.w;
      int kk = idx >> 5, nv = idx & 31;
      float4 vb = ld4(Bb + (size_t)(k0 + kk) * N + nv * 4);
      *(float4*)&Bs[kk][nv * 4] = vb;
    }
    __syncthreads();
#pragma unroll
    for (int kk = 0; kk < 16; kk++) {
      float a[8], bb[8];
      *(float4*)&a[0] = *(const float4*)&As[kk][ty * 8];
      *(float4*)&a[4] = *(const float4*)&As[kk][ty * 8 + 4];
      *(float4*)&bb[0] = *(const float4*)&Bs[kk][tx * 8];
      *(float4*)&bb[4] = *(const float4*)&Bs[kk][tx * 8 + 4];
#pragma unroll
      for (int i = 0; i < 8; i++)
#pragma unroll
        for (int j = 0; j < 8; j++) acc[i][j] = fmaf(a[i], bb[j], acc[i][j]);
    }
  }
  const int row0 = by * 128 + ty * 8;
  const int col0 = bx * 128 + tx * 8;
  float bv[8];
  *(float4*)&bv[0] = *(const float4*)&bias[col0];
  *(float4*)&bv[4] = *(const float4*)&bias[col0 + 4];
#pragma unroll
  for (int i = 0; i < 8; i++) {
    float4 o0 = make_float4(acc[i][0] + bv[0], acc[i][1] + bv[1],
                            acc[i][2] + bv[2], acc[i][3] + bv[3]);
    float4 o1 = make_float4(acc[i][4] + bv[4], acc[i][5] + bv[5],
                            acc[i][6] + bv[6], acc[i][7] + bv[7]);
    st4(&C[(size_t)(row0 + i) * N + col0], o0);
    st4(&C[(size_t)(row0 + i) * N + col0 + 4], o1);
  }
}

// ---------------- persistent bidirectional LSTM scan (one layer) ----------------
// 256 WGs x 512 threads; chain=(dir,b) -> 16 WGs; WG owns 32 hidden units.
// Wh columns in VGPRs (128/thread). h exchange: 64-bit packed (tag | fp32 h).
// Adaptive path: if all 16 WGs of a chain share an XCD (HW_REG_XCC_ID probe),
// use sc0 (L2-local, ~5x lower latency) loads/stores; else agent scope (LLC).
// Producers dual-store (sc0 + agent); spinners escalate sc0->agent after 1024
// tries, so a wrong co-location guess degrades to slow-but-correct, never
// silently wrong. Tags unique per scan launch (bases 1 / 3000): stale lines
// from other dispatches/replays can never alias except bit-identically.
__device__ __forceinline__ float sigmf_(float x) { return 1.f / (1.f + expf(-x)); }

__global__ __launch_bounds__(512, 2) void lstm_scan(
    const __half* __restrict__ Pf, const __half* __restrict__ Pb,
    const float* __restrict__ Whf, const float* __restrict__ Whb,
    const int* __restrict__ seqlen, __half* __restrict__ cat,
    unsigned long long* hbuf, unsigned* ctrl, float* diag, int tagbase) {
  const int w = blockIdx.x;
  const int chain = w & 15;
  const int us = w >> 4;
  const int dir = chain & 1;
  const int b = chain >> 1;
  const int t = threadIdx.x;
  const int col = t & 127;
  const int kc = t >> 7;
  const int C = (col >> 5) * HH + us * 32 + (col & 31);

  const float* __restrict__ Wh = dir ? Whb : Whf;
  const __half* __restrict__ P = dir ? Pb : Pf;
  const int L = seqlen[b];

  __shared__ float h_lds[HH];
  __shared__ float partial[4][128];
  __shared__ int s_fast;

  // ---- one-time co-location detection (per chain) ----
  {
    int xcd = 0;
    asm volatile("s_getreg_b32 %0, hwreg(HW_REG_XCC_ID)" : "=s"(xcd));
    if (t == 0) {
      __hip_atomic_fetch_or(&ctrl[chain], 1u << (xcd & 31), __ATOMIC_RELAXED,
                            __HIP_MEMORY_SCOPE_AGENT);
      __hip_atomic_fetch_add(&ctrl[16 + chain], 1u, __ATOMIC_RELEASE,
                             __HIP_MEMORY_SCOPE_AGENT);
      int ok = 1, tries = 0;
      while (__hip_atomic_load(&ctrl[16 + chain], __ATOMIC_ACQUIRE,
                               __HIP_MEMORY_SCOPE_AGENT) < 16u) {
        if (++tries > (1 << 20)) { ok = 0; break; }
      }
      unsigned m = __hip_atomic_load(&ctrl[chain], __ATOMIC_RELAXED,
                                     __HIP_MEMORY_SCOPE_AGENT);
      s_fast = ok && (__popc(m) == 1);
    }
    __syncthreads();
  }
  const int fast = s_fast;

  float wr[128];
  {
    const float* wp = Wh + (size_t)(kc * 128) * G4 + C;
#pragma unroll
    for (int j = 0; j < 128; j++) wr[j] = wp[(size_t)j * G4];
  }
  float c_state = 0.f;

  unsigned long long* hb_base = hbuf + ((size_t)dir * NB + b) * HH;
  const size_t slotStride = (size_t)2 * NB * HH;
  const unsigned tb = (unsigned)tagbase;

  // init: h(-1)=0 with tag=tagbase into slot 0 for own units (dual store)
  if (t < 32) {
    unsigned long long pv = ((unsigned long long)tb << 32);
    unsigned long long* hp = hb_base + us * 32 + t;
    unsigned long long aa = (unsigned long long)hp;
    asm volatile("global_store_dwordx2 %0, %1, off sc0" ::"v"(aa), "v"(pv)
                 : "memory");
    __hip_atomic_store(hp, pv, __ATOMIC_RELAXED, __HIP_MEMORY_SCOPE_AGENT);
  }

  for (int s = 0; s < T_LEN; s++) {
    const int tin = dir ? ((s < L) ? (L - 1 - s) : s) : s;
    float p0 = 0.f, p1 = 0.f, p2 = 0.f, p3 = 0.f;
    if (t < 32) {
      const __half* pr = P + ((size_t)b * T_LEN + tin) * G4 + us * 32 + t;
      p0 = __half2float(pr[0]);
      p1 = __half2float(pr[HH]);
      p2 = __half2float(pr[2 * HH]);
      p3 = __half2float(pr[3 * HH]);
    }

    // spin: unit t must carry tag == tb+s
    int dead = 0;
    {
      const unsigned want = tb + (unsigned)s;
      unsigned long long* hp = hb_base + (size_t)(s & 1) * slotStride + t;
      unsigned long long aa = (unsigned long long)hp;
      unsigned long long v;
      int tries = 0, esc = !fast;
      for (;;) {
        if (!esc) {
          asm volatile(
              "global_load_dwordx2 %0, %1, off sc0\n\ts_waitcnt vmcnt(0)"
              : "=v"(v)
              : "v"(aa)
              : "memory");
        } else {
          v = __hip_atomic_load(hp, __ATOMIC_RELAXED, __HIP_MEMORY_SCOPE_AGENT);
        }
        if ((unsigned)(v >> 32) == want) break;
        ++tries;
        if (tries == 1024) esc = 1;           // safety net: escalate to LLC path
        if (tries > (1 << 20)) { dead = 1; break; }
      }
      h_lds[t] = __uint_as_float((unsigned)v);
    }
    if (__syncthreads_or(dead)) {
      if (t == 0) { atomicAdd(diag + 1, 1.0f); diag[2] = (float)s; }
      break;
    }

    float a0 = 0.f, a1 = 0.f, a2 = 0.f, a3 = 0.f;
    const float* hk = &h_lds[kc * 128];
#pragma unroll
    for (int jj = 0; jj < 32; jj++) {
      float4 hv = *(const float4*)&hk[jj * 4];
      a0 = fmaf(hv.x, wr[jj * 4 + 0], a0);
      a1 = fmaf(hv.y, wr[jj * 4 + 1], a1);
      a2 = fmaf(hv.z, wr[jj * 4 + 2], a2);
      a3 = fmaf(hv.w, wr[jj * 4 + 3], a3);
    }
    partial[kc][col] = (a0 + a1) + (a2 + a3);
    __syncthreads();

    if (t < 32) {
      float g0 = p0, g1 = p1, g2 = p2, g3 = p3;
#pragma unroll
      for (int k2 = 0; k2 < 4; k2++) {
        g0 += partial[k2][t];
        g1 += partial[k2][32 + t];
        g2 += partial[k2][64 + t];
        g3 += partial[k2][96 + t];
      }
      c_state = sigmf_(g1) * c_state + sigmf_(g0) * tanhf(g2);
      float hn = sigmf_(g3) * tanhf(c_state);
      unsigned long long pv =
          ((unsigned long long)(tb + (unsigned)s + 1u) << 32) |
          (unsigned long long)__float_as_uint(hn);
      unsigned long long* hp =
          hb_base + (size_t)((s + 1) & 1) * slotStride + us * 32 + t;
      unsigned long long aa = (unsigned long long)hp;
      asm volatile("global_store_dwordx2 %0, %1, off sc0" ::"v"(aa), "v"(pv)
                   : "memory");
      __hip_atomic_store(hp, pv, __ATOMIC_RELAXED, __HIP_MEMORY_SCOPE_AGENT);
      cat[((size_t)b * T_LEN + tin) * CAT2H + dir * HH + us * 32 + t] =
          __float2half(hn);
    }
  }
}

// Failure-signature marker: writes a decodable code into out[0] ONLY on failure.
__global__ void diag_mark(const float* diag, float* out, float code_ws, int wsfail) {
  if (wsfail) { out[0] = code_ws; return; }
  float nd = diag[1];
  if (nd > 0.f) out[0] = 1.0e7f + nd * 1.0e4f + diag[2];
}

extern "C" void kernel_launch(void* const* d_in, const int* in_sizes, int n_in,
                              void* d_out, int out_size, void* d_ws, size_t ws_size,
                              hipStream_t stream) {
  const float* inputs = (const float*)d_in[0];
  const int* seqlen = (const int*)d_in[1];
  const float* Wx_f = (const float*)d_in[2];
  const float* Wh_f = (const float*)d_in[3];
  const float* b_f  = (const float*)d_in[4];
  const float* Wx_b = (const float*)d_in[5];
  const float* Wh_b = (const float*)d_in[6];
  const float* b_b  = (const float*)d_in[7];
  const float* Wp   = (const float*)d_in[8];
  const float* bp   = (const float*)d_in[9];
  float* out = (float*)d_out;

  // ws layout: diag(64B) | ctrl: scan0(128B)+scan1(128B) @64..320 | pad |
  //            hbuf u64 @512 (128KiB) | Pf | Pb | cat | x1 (fp16)
  const size_t oHB = 512;
  const size_t szHB = (size_t)2 * 2 * NB * HH * sizeof(unsigned long long);  // 131072
  const size_t oPf = oHB + szHB;
  const size_t oPb = oPf + 67108864ull;
  const size_t oCat = oPb + 67108864ull;
  const size_t oX1 = oCat + 33554432ull;
  const size_t need = oX1 + 16777216ull;

  if (ws_size < need) {
    hipMemsetAsync(d_out, 0, (size_t)out_size * sizeof(float), stream);
    float code = 1.0e8f + (float)(ws_size / (1024.0 * 1024.0)) * 10.0f;
    diag_mark<<<1, 1, 0, stream>>>(nullptr, out, code, 1);
    return;
  }
  char* ws = (char*)d_ws;
  float* diag = (float*)ws;
  unsigned* ctrl0 = (unsigned*)(ws + 64);
  unsigned* ctrl1 = (unsigned*)(ws + 192);
  unsigned long long* hbuf = (unsigned long long*)(ws + oHB);
  __half* Pf = (__half*)(ws + oPf);
  __half* Pb = (__half*)(ws + oPb);
  __half* cat = (__half*)(ws + oCat);
  __half* x1 = (__half*)(ws + oX1);

  hipMemsetAsync(ws, 0, 512, stream);  // diag + ctrl for both scans

  const int MM = NB * T_LEN;  // 16384

  // ---- layer 0 (A = fp32 inputs) ----
  gemm_bias<float, __half><<<dim3((MM / 128) * (G4 / 128)), dim3(256), 0, stream>>>(
      inputs, Wx_f, b_f, Pf, MM, G4, DD);
  gemm_bias<float, __half><<<dim3((MM / 128) * (G4 / 128)), dim3(256), 0, stream>>>(
      inputs, Wx_b, b_b, Pb, MM, G4, DD);
  lstm_scan<<<dim3(256), dim3(512), 0, stream>>>(Pf, Pb, Wh_f, Wh_b, seqlen, cat,
                                                 hbuf, ctrl0, diag, 1);
  gemm_bias<__half, __half><<<dim3((MM / 128) * (DD / 128)), dim3(256), 0, stream>>>(
      cat, Wp, bp, x1, MM, DD, CAT2H);

  // ---- layer 1 (A = fp16 x1) ----
  gemm_bias<__half, __half><<<dim3((MM / 128) * (G4 / 128)), dim3(256), 0, stream>>>(
      x1, Wx_f + (size_t)DD * G4, b_f + G4, Pf, MM, G4, DD);
  gemm_bias<__half, __half><<<dim3((MM / 128) * (G4 / 128)), dim3(256), 0, stream>>>(
      x1, Wx_b + (size_t)DD * G4, b_b + G4, Pb, MM, G4, DD);
  lstm_scan<<<dim3(256), dim3(512), 0, stream>>>(
      Pf, Pb, Wh_f + (size_t)HH * G4, Wh_b + (size_t)HH * G4, seqlen, cat, hbuf,
      ctrl1, diag, 3000);
  gemm_bias<__half, float><<<dim3((MM / 128) * (DD / 128)), dim3(256), 0, stream>>>(
      cat, Wp + (size_t)CAT2H * DD, bp + DD, out, MM, DD, CAT2H);

  diag_mark<<<1, 1, 0, stream>>>(diag, out, 0.f, 0);
}

// Round 5
// 10295.281 us; speedup vs baseline: 59.7475x; 59.7475x over previous
//
#include <hip/hip_runtime.h>
#include <hip/hip_fp16.h>
#include <math.h>

#define T_LEN 2048
#define NB 8
#define DD 512
#define HH 512
#define G4 2048   // 4*H
#define CAT2H 1024

// ---------- vector load/store helpers (fp32 or fp16 <-> float4) ----------
__device__ __forceinline__ float4 ld4(const float* p) { return *(const float4*)p; }
__device__ __forceinline__ float4 ld4(const __half* p) {
  const __half2 a = *(const __half2*)p;
  const __half2 b = *(const __half2*)(p + 2);
  return make_float4(__half2float(a.x), __half2float(a.y),
                     __half2float(b.x), __half2float(b.y));
}
__device__ __forceinline__ void st4(float* p, float4 v) { *(float4*)p = v; }
__device__ __forceinline__ void st4(__half* p, float4 v) {
  *(__half2*)p = __floats2half2_rn(v.x, v.y);
  *(__half2*)(p + 2) = __floats2half2_rn(v.z, v.w);
}

// ---------------- tiled GEMM with bias: C = A(MxK) @ B(KxN) + bias ----------------
template <typename TA, typename TC>
__global__ __launch_bounds__(256) void gemm_bias(
    const TA* __restrict__ A, const float* __restrict__ B,
    const float* __restrict__ bias, TC* __restrict__ C,
    int M, int N, int K) {
  __shared__ float As[16][128];
  __shared__ float Bs[16][128];
  const int nTiles = N >> 7;
  const int bx = blockIdx.x % nTiles;
  const int by = blockIdx.x / nTiles;
  const int tid = threadIdx.x;
  const int tx = tid & 15, ty = tid >> 4;
  const TA* Ab = A + (size_t)by * 128 * K;
  const float* Bb = B + ((size_t)bx << 7);
  float acc[8][8];
#pragma unroll
  for (int i = 0; i < 8; i++)
#pragma unroll
    for (int j = 0; j < 8; j++) acc[i][j] = 0.f;

  for (int k0 = 0; k0 < K; k0 += 16) {
    __syncthreads();
#pragma unroll
    for (int i = 0; i < 2; i++) {
      int idx = i * 256 + tid;
      int m = idx >> 2, kv = idx & 3;
      float4 va = ld4(Ab + (size_t)m * K + k0 + kv * 4);
      As[kv * 4 + 0][m] = va.x;
      As[kv * 4 + 1][m] = va.y;
      As[kv * 4 + 2][m] = va.z;
      As[kv * 4 + 3][m] = va.w;
      int kk = idx >> 5, nv = idx & 31;
      float4 vb = ld4(Bb + (size_t)(k0 + kk) * N + nv * 4);
      *(float4*)&Bs[kk][nv * 4] = vb;
    }
    __syncthreads();
#pragma unroll
    for (int kk = 0; kk < 16; kk++) {
      float a[8], bb[8];
      *(float4*)&a[0] = *(const float4*)&As[kk][ty * 8];
      *(float4*)&a[4] = *(const float4*)&As[kk][ty * 8 + 4];
      *(float4*)&bb[0] = *(const float4*)&Bs[kk][tx * 8];
      *(float4*)&bb[4] = *(const float4*)&Bs[kk][tx * 8 + 4];
#pragma unroll
      for (int i = 0; i < 8; i++)
#pragma unroll
        for (int j = 0; j < 8; j++) acc[i][j] = fmaf(a[i], bb[j], acc[i][j]);
    }
  }
  const int row0 = by * 128 + ty * 8;
  const int col0 = bx * 128 + tx * 8;
  float bv[8];
  *(float4*)&bv[0] = *(const float4*)&bias[col0];
  *(float4*)&bv[4] = *(const float4*)&bias[col0 + 4];
#pragma unroll
  for (int i = 0; i < 8; i++) {
    float4 o0 = make_float4(acc[i][0] + bv[0], acc[i][1] + bv[1],
                            acc[i][2] + bv[2], acc[i][3] + bv[3]);
    float4 o1 = make_float4(acc[i][4] + bv[4], acc[i][5] + bv[5],
                            acc[i][6] + bv[6], acc[i][7] + bv[7]);
    st4(&C[(size_t)(row0 + i) * N + col0], o0);
    st4(&C[(size_t)(row0 + i) * N + col0 + 4], o1);
  }
}

// ---------------- persistent bidirectional LSTM scan (one layer) ----------------
// 256 WGs x 512 threads; chain=(dir,b) -> 16 WGs; WG owns 32 hidden units.
// Wh columns in VGPRs (128/thread). h exchange: 64-bit packed (tag | fp32 h)
// relaxed AGENT-scope atomics through the LLC (per-XCD L2 is not coherent;
// sc0 fast-path experiment in R4 proved stale-L2 spins cost 70x — do not
// retry intra-XCD exchange). Tags unique per scan launch (bases 1 / 3000):
// slot reuse across launches/replays can only alias bit-identically (benign).
__device__ __forceinline__ float sigmf_(float x) {
  return 1.f / (1.f + __expf(-x));   // v_exp + v_rcp, ~1e-6 rel
}
__device__ __forceinline__ float tanhf_(float x) {
  return 1.f - 2.f / (1.f + __expf(2.f * x));
}

__global__ __launch_bounds__(512, 2) void lstm_scan(
    const __half* __restrict__ Pf, const __half* __restrict__ Pb,
    const float* __restrict__ Whf, const float* __restrict__ Whb,
    const int* __restrict__ seqlen, __half* __restrict__ cat,
    unsigned long long* hbuf, float* diag, int tagbase) {
  const int w = blockIdx.x;
  const int chain = w & 15;
  const int us = w >> 4;
  const int dir = chain & 1;
  const int b = chain >> 1;
  const int t = threadIdx.x;
  const int col = t & 127;
  const int kc = t >> 7;
  const int C = (col >> 5) * HH + us * 32 + (col & 31);

  const float* __restrict__ Wh = dir ? Whb : Whf;
  const __half* __restrict__ P = dir ? Pb : Pf;
  const int L = seqlen[b];

  __shared__ float h_lds[HH];
  __shared__ float partial[4][128];

  float wr[128];
  {
    const float* wp = Wh + (size_t)(kc * 128) * G4 + C;
#pragma unroll
    for (int j = 0; j < 128; j++) wr[j] = wp[(size_t)j * G4];
  }
  float c_state = 0.f;

  // hbuf layout: [slot(2)][dir(2)][b(8)][H] as u64 (tag<<32 | f32 h bits)
  unsigned long long* hb_base = hbuf + ((size_t)dir * NB + b) * HH;
  const size_t slotStride = (size_t)2 * NB * HH;
  const unsigned tb = (unsigned)tagbase;

  // init: h(-1)=0 with tag=tb into slot 0 for own units
  if (t < 32) {
    unsigned long long pv = ((unsigned long long)tb << 32);
    __hip_atomic_store(hb_base + us * 32 + t, pv, __ATOMIC_RELAXED,
                       __HIP_MEMORY_SCOPE_AGENT);
  }

  for (int s = 0; s < T_LEN; s++) {
    const int tin = dir ? ((s < L) ? (L - 1 - s) : s) : s;
    float p0 = 0.f, p1 = 0.f, p2 = 0.f, p3 = 0.f;
    if (t < 32) {  // prefetch P for the finale; latency hidden under the spin
      const __half* pr = P + ((size_t)b * T_LEN + tin) * G4 + us * 32 + t;
      p0 = __half2float(pr[0]);
      p1 = __half2float(pr[HH]);
      p2 = __half2float(pr[2 * HH]);
      p3 = __half2float(pr[3 * HH]);
    }

    // spin: unit t must carry tag == tb+s
    int dead = 0;
    {
      const unsigned want = tb + (unsigned)s;
      unsigned long long* hp = hb_base + (size_t)(s & 1) * slotStride + t;
      unsigned long long v;
      int tries = 0;
      for (;;) {
        v = __hip_atomic_load(hp, __ATOMIC_RELAXED, __HIP_MEMORY_SCOPE_AGENT);
        if ((unsigned)(v >> 32) == want) break;
        if (++tries > (1 << 20)) { dead = 1; break; }
      }
      h_lds[t] = __uint_as_float((unsigned)v);
    }
    if (__syncthreads_or(dead)) {  // barrier #1 (also fences h_lds)
      if (t == 0) { atomicAdd(diag + 1, 1.0f); diag[2] = (float)s; }
      break;
    }

    float a0 = 0.f, a1 = 0.f, a2 = 0.f, a3 = 0.f;
    const float* hk = &h_lds[kc * 128];
#pragma unroll
    for (int jj = 0; jj < 32; jj++) {
      float4 hv = *(const float4*)&hk[jj * 4];
      a0 = fmaf(hv.x, wr[jj * 4 + 0], a0);
      a1 = fmaf(hv.y, wr[jj * 4 + 1], a1);
      a2 = fmaf(hv.z, wr[jj * 4 + 2], a2);
      a3 = fmaf(hv.w, wr[jj * 4 + 3], a3);
    }
    partial[kc][col] = (a0 + a1) + (a2 + a3);
    __syncthreads();  // barrier #2

    if (t < 32) {
      float g0 = p0, g1 = p1, g2 = p2, g3 = p3;
#pragma unroll
      for (int k2 = 0; k2 < 4; k2++) {
        g0 += partial[k2][t];
        g1 += partial[k2][32 + t];
        g2 += partial[k2][64 + t];
        g3 += partial[k2][96 + t];
      }
      c_state = sigmf_(g1) * c_state + sigmf_(g0) * tanhf_(g2);
      float hn = sigmf_(g3) * tanhf_(c_state);
      // publish h FIRST (critical path), then the cat store
      unsigned long long pv =
          ((unsigned long long)(tb + (unsigned)s + 1u) << 32) |
          (unsigned long long)__float_as_uint(hn);
      __hip_atomic_store(hb_base + (size_t)((s + 1) & 1) * slotStride + us * 32 + t,
                         pv, __ATOMIC_RELAXED, __HIP_MEMORY_SCOPE_AGENT);
      cat[((size_t)b * T_LEN + tin) * CAT2H + dir * HH + us * 32 + t] =
          __float2half(hn);
    }
    // no trailing barrier: next-step h_lds/partial writes are gated by
    // barrier #1 of step s+1 (requires finale threads to pass through here).
  }
}

// Failure-signature marker: writes a decodable code into out[0] ONLY on failure.
__global__ void diag_mark(const float* diag, float* out, float code_ws, int wsfail) {
  if (wsfail) { out[0] = code_ws; return; }
  float nd = diag[1];
  if (nd > 0.f) out[0] = 1.0e7f + nd * 1.0e4f + diag[2];
}

extern "C" void kernel_launch(void* const* d_in, const int* in_sizes, int n_in,
                              void* d_out, int out_size, void* d_ws, size_t ws_size,
                              hipStream_t stream) {
  const float* inputs = (const float*)d_in[0];
  const int* seqlen = (const int*)d_in[1];
  const float* Wx_f = (const float*)d_in[2];
  const float* Wh_f = (const float*)d_in[3];
  const float* b_f  = (const float*)d_in[4];
  const float* Wx_b = (const float*)d_in[5];
  const float* Wh_b = (const float*)d_in[6];
  const float* b_b  = (const float*)d_in[7];
  const float* Wp   = (const float*)d_in[8];
  const float* bp   = (const float*)d_in[9];
  float* out = (float*)d_out;

  // ws layout: diag(256B) | hbuf u64 @256 (128KiB) | Pf | Pb | cat | x1 (fp16)
  const size_t oHB = 256;
  const size_t szHB = (size_t)2 * 2 * NB * HH * sizeof(unsigned long long);  // 131072
  const size_t oPf = oHB + szHB;
  const size_t oPb = oPf + 67108864ull;
  const size_t oCat = oPb + 67108864ull;
  const size_t oX1 = oCat + 33554432ull;
  const size_t need = oX1 + 16777216ull;

  if (ws_size < need) {
    hipMemsetAsync(d_out, 0, (size_t)out_size * sizeof(float), stream);
    float code = 1.0e8f + (float)(ws_size / (1024.0 * 1024.0)) * 10.0f;
    diag_mark<<<1, 1, 0, stream>>>(nullptr, out, code, 1);
    return;
  }
  char* ws = (char*)d_ws;
  float* diag = (float*)ws;
  unsigned long long* hbuf = (unsigned long long*)(ws + oHB);
  __half* Pf = (__half*)(ws + oPf);
  __half* Pb = (__half*)(ws + oPb);
  __half* cat = (__half*)(ws + oCat);
  __half* x1 = (__half*)(ws + oX1);

  hipMemsetAsync(diag, 0, 256, stream);

  const int MM = NB * T_LEN;  // 16384

  // ---- layer 0 (A = fp32 inputs) ----
  gemm_bias<float, __half><<<dim3((MM / 128) * (G4 / 128)), dim3(256), 0, stream>>>(
      inputs, Wx_f, b_f, Pf, MM, G4, DD);
  gemm_bias<float, __half><<<dim3((MM / 128) * (G4 / 128)), dim3(256), 0, stream>>>(
      inputs, Wx_b, b_b, Pb, MM, G4, DD);
  lstm_scan<<<dim3(256), dim3(512), 0, stream>>>(Pf, Pb, Wh_f, Wh_b, seqlen, cat,
                                                 hbuf, diag, 1);
  gemm_bias<__half, __half><<<dim3((MM / 128) * (DD / 128)), dim3(256), 0, stream>>>(
      cat, Wp, bp, x1, MM, DD, CAT2H);

  // ---- layer 1 (A = fp16 x1) ----
  gemm_bias<__half, __half><<<dim3((MM / 128) * (G4 / 128)), dim3(256), 0, stream>>>(
      x1, Wx_f + (size_t)DD * G4, b_f + G4, Pf, MM, G4, DD);
  gemm_bias<__half, __half><<<dim3((MM / 128) * (G4 / 128)), dim3(256), 0, stream>>>(
      x1, Wx_b + (size_t)DD * G4, b_b + G4, Pb, MM, G4, DD);
  lstm_scan<<<dim3(256), dim3(512), 0, stream>>>(
      Pf, Pb, Wh_f + (size_t)HH * G4, Wh_b + (size_t)HH * G4, seqlen, cat, hbuf,
      diag, 3000);
  gemm_bias<__half, float><<<dim3((MM / 128) * (DD / 128)), dim3(256), 0, stream>>>(
      cat, Wp + (size_t)CAT2H * DD, bp + DD, out, MM, DD, CAT2H);

  diag_mark<<<1, 1, 0, stream>>>(diag, out, 0.f, 0);
}